// Round 1
// baseline (473.320 us; speedup 1.0000x reference)
//
#include <hip/hip_runtime.h>
#include <cstdint>
#include <cstddef>

#define IN_F 4096
#define OUT_F 4096

typedef __attribute__((ext_vector_type(8))) short bf16x8;
typedef __attribute__((ext_vector_type(4))) float f32x4;

__device__ __forceinline__ ushort f32_bf16_rne(float f) {
    uint32_t u = __builtin_bit_cast(uint32_t, f);
    uint32_t r = (u + 0x7FFFu + ((u >> 16) & 1u)) >> 16;
    return (ushort)r;
}

__device__ __forceinline__ void gload_lds16(const void* g, void* l) {
    __builtin_amdgcn_global_load_lds(
        (const __attribute__((address_space(1))) uint32_t*)g,
        (__attribute__((address_space(3))) uint32_t*)l,
        16, 0, 0);
}

// ---------- deterministic |W| reduction (fixed order, no atomics) ----------
__global__ void reduce_abs1(const float* __restrict__ W, float* __restrict__ part) {
    __shared__ float sm[256];
    const int b = blockIdx.x, t = threadIdx.x;
    const float* p = W + (size_t)b * 4096;
    float s = 0.f;
#pragma unroll
    for (int j = 0; j < 16; ++j) s += fabsf(p[t + 256 * j]);
    sm[t] = s;
    __syncthreads();
    for (int w = 128; w > 0; w >>= 1) {
        if (t < w) sm[t] += sm[t + w];
        __syncthreads();
    }
    if (t == 0) part[b] = sm[0];
}

__global__ void reduce_abs2(const float* __restrict__ part, float* __restrict__ scale) {
    __shared__ float sm[256];
    const int t = threadIdx.x;
    float s = 0.f;
#pragma unroll
    for (int j = 0; j < 16; ++j) s += part[t + 256 * j];
    sm[t] = s;
    __syncthreads();
    for (int w = 128; w > 0; w >>= 1) {
        if (t < w) sm[t] += sm[t + w];
        __syncthreads();
    }
    if (t == 0) {
        float m = sm[0] / 16777216.0f;  // mean over 4096*4096
        *scale = fmaxf(m, 1e-8f);
    }
}

// ---------- quantize W -> bf16 {-2,-1,0,1,2} (exact in bf16) ----------
__global__ void quantize_w(const float* __restrict__ W, ushort* __restrict__ wq,
                           const float* __restrict__ scale_p) {
    const int i = blockIdx.x * 256 + threadIdx.x;  // one float4
    const float s = *scale_p;
    float4 v = ((const float4*)W)[i];
    float q0 = fminf(fmaxf(rintf(v.x / s), -2.f), 2.f);
    float q1 = fminf(fmaxf(rintf(v.y / s), -2.f), 2.f);
    float q2 = fminf(fmaxf(rintf(v.z / s), -2.f), 2.f);
    float q3 = fminf(fmaxf(rintf(v.w / s), -2.f), 2.f);
    ushort4 o;
    o.x = f32_bf16_rne(q0); o.y = f32_bf16_rne(q1);
    o.z = f32_bf16_rne(q2); o.w = f32_bf16_rne(q3);
    ((ushort4*)wq)[i] = o;
}

// ---------- cast x -> bf16 (RNE) ----------
__global__ void cast_x(const float* __restrict__ X, ushort* __restrict__ xh) {
    const int i = blockIdx.x * 256 + threadIdx.x;  // one float4
    float4 v = ((const float4*)X)[i];
    ushort4 o;
    o.x = f32_bf16_rne(v.x); o.y = f32_bf16_rne(v.y);
    o.z = f32_bf16_rne(v.z); o.w = f32_bf16_rne(v.w);
    ((ushort4*)xh)[i] = o;
}

// ---------- bf16 MFMA GEMM: C = scale * (A @ Bq^T) ----------
// A: [M][K] (bf16 if ABF16 else fp32), Bq: [N][K] bf16 (K-contiguous, "B^T" input)
// 128x128 tile, BK=64, 256 threads = 4 waves (2x2), each wave 64x64 via 4x4
// frags of mfma_f32_16x16x32_bf16.
template <bool ABF16>
__global__ __launch_bounds__(256) void qgemm(const void* __restrict__ Aptr,
                                             const ushort* __restrict__ Bq,
                                             float* __restrict__ C,
                                             const float* __restrict__ scale_p,
                                             int M, int N, int K) {
    __shared__ __align__(16) ushort sA[128 * 64];
    __shared__ __align__(16) ushort sB[128 * 64];

    const int t = threadIdx.x;
    const int lane = t & 63;
    const int w = t >> 6;
    const int wr = w >> 1, wc = w & 1;

    // XCD-bijective block swizzle (grid % 8 == 0 here)
    const int nwg = gridDim.x;
    int wg = blockIdx.x;
    if ((nwg & 7) == 0) wg = (wg & 7) * (nwg >> 3) + (wg >> 3);
    const int MT = M >> 7;
    const int mt = wg % MT;
    const int nt = wg / MT;
    const int m0 = mt * 128, n0 = nt * 128;

    const ushort* Ab = (const ushort*)Aptr;
    const float* Af = (const float*)Aptr;

    f32x4 zero = {0.f, 0.f, 0.f, 0.f};
    f32x4 acc[4][4];
#pragma unroll
    for (int m = 0; m < 4; ++m)
#pragma unroll
        for (int n = 0; n < 4; ++n) acc[m][n] = zero;

    for (int k0 = 0; k0 < K; k0 += 64) {
        // stage B tile (128x64 bf16) via async global->LDS, width 16
#pragma unroll
        for (int i = 0; i < 4; ++i) {
            int e = i * 2048 + t * 8;
            int r = e >> 6, c = e & 63;
            gload_lds16(Bq + (size_t)(n0 + r) * K + (k0 + c), &sB[e]);
        }
        if constexpr (ABF16) {
#pragma unroll
            for (int i = 0; i < 4; ++i) {
                int e = i * 2048 + t * 8;
                int r = e >> 6, c = e & 63;
                gload_lds16(Ab + (size_t)(m0 + r) * K + (k0 + c), &sA[e]);
            }
        } else {
            // reg-stage fp32 A tile, convert to bf16, ds_write_b128
#pragma unroll
            for (int i = 0; i < 4; ++i) {
                int e = i * 2048 + t * 8;
                int r = e >> 6, c = e & 63;
                const float* src = Af + (size_t)(m0 + r) * K + (k0 + c);
                float4 v0 = *(const float4*)src;
                float4 v1 = *(const float4*)(src + 4);
                bf16x8 pk;
                pk[0] = (short)f32_bf16_rne(v0.x); pk[1] = (short)f32_bf16_rne(v0.y);
                pk[2] = (short)f32_bf16_rne(v0.z); pk[3] = (short)f32_bf16_rne(v0.w);
                pk[4] = (short)f32_bf16_rne(v1.x); pk[5] = (short)f32_bf16_rne(v1.y);
                pk[6] = (short)f32_bf16_rne(v1.z); pk[7] = (short)f32_bf16_rne(v1.w);
                *(bf16x8*)&sA[e] = pk;
            }
        }
        __syncthreads();  // compiler emits vmcnt(0)+lgkmcnt(0) drain before barrier

#pragma unroll
        for (int ks = 0; ks < 2; ++ks) {
            const int kk = ks * 32 + ((lane >> 4) << 3);
            bf16x8 afr[4], bfr[4];
#pragma unroll
            for (int m = 0; m < 4; ++m)
                afr[m] = *(const bf16x8*)&sA[(wr * 64 + m * 16 + (lane & 15)) * 64 + kk];
#pragma unroll
            for (int n = 0; n < 4; ++n)
                bfr[n] = *(const bf16x8*)&sB[(wc * 64 + n * 16 + (lane & 15)) * 64 + kk];
#pragma unroll
            for (int m = 0; m < 4; ++m)
#pragma unroll
                for (int n = 0; n < 4; ++n)
                    acc[m][n] = __builtin_amdgcn_mfma_f32_16x16x32_bf16(
                        afr[m], bfr[n], acc[m][n], 0, 0, 0);
        }
        __syncthreads();
    }

    const float s = *scale_p;
#pragma unroll
    for (int m = 0; m < 4; ++m)
#pragma unroll
        for (int n = 0; n < 4; ++n) {
            const int col = n0 + wc * 64 + n * 16 + (lane & 15);
            const int rbase = m0 + wr * 64 + m * 16 + ((lane >> 4) << 2);
#pragma unroll
            for (int j = 0; j < 4; ++j)
                C[(size_t)(rbase + j) * N + col] = s * acc[m][n][j];
        }
}

// ---------- last-resort naive path (only if ws is tiny) ----------
__global__ void naive_qgemm(const float* __restrict__ X, const float* __restrict__ W,
                            float* __restrict__ out, const float* __restrict__ scale_p,
                            int M) {
    const int col = blockIdx.x * 256 + threadIdx.x;
    const int row = blockIdx.y;
    const float s = *scale_p;
    const float inv = 1.0f / s;
    const float* xr = X + (size_t)row * IN_F;
    const float* wrow = W + (size_t)col * IN_F;
    float acc = 0.f;
    for (int k = 0; k < IN_F; ++k) {
        float q = fminf(fmaxf(rintf(wrow[k] * inv), -2.f), 2.f);
        acc += xr[k] * q;
    }
    out[(size_t)row * OUT_F + col] = acc * s;
}

extern "C" void kernel_launch(void* const* d_in, const int* in_sizes, int n_in,
                              void* d_out, int out_size, void* d_ws, size_t ws_size,
                              hipStream_t stream) {
    const float* x = (const float*)d_in[0];
    const float* W = (const float*)d_in[1];
    float* out = (float*)d_out;
    const int M = in_sizes[0] / IN_F;  // 8192
    const int K = IN_F, N = OUT_F;

    char* ws = (char*)d_ws;
    const size_t OFF_PART = 512;
    const size_t OFF_WQ = OFF_PART + 4096 * sizeof(float);        // 16896 (16B-aligned)
    const size_t WQ_BYTES = (size_t)N * K * sizeof(ushort);       // 33.5 MB
    const size_t OFF_XH = OFF_WQ + WQ_BYTES;
    const size_t XH_BYTES = (size_t)M * K * sizeof(ushort);       // 67 MB
    float* scale = (float*)(ws + 0);
    float* part = (float*)(ws + OFF_PART);
    ushort* wq = (ushort*)(ws + OFF_WQ);
    ushort* xh = (ushort*)(ws + OFF_XH);

    if (ws_size < OFF_WQ) return;  // cannot even hold reduction scratch (not expected)

    // scale = max(mean|W|, 1e-8), deterministic fixed-order reduction
    reduce_abs1<<<4096, 256, 0, stream>>>(W, part);
    reduce_abs2<<<1, 256, 0, stream>>>(part, scale);

    const int gemm_grid = (M / 128) * (N / 128);  // 2048

    if (ws_size >= OFF_XH + XH_BYTES) {
        quantize_w<<<(N * K / 4) / 256, 256, 0, stream>>>(W, wq, scale);
        cast_x<<<(M * K / 4) / 256, 256, 0, stream>>>(x, xh);
        qgemm<true><<<gemm_grid, 256, 0, stream>>>(xh, wq, out, scale, M, N, K);
    } else if (ws_size >= OFF_WQ + WQ_BYTES) {
        quantize_w<<<(N * K / 4) / 256, 256, 0, stream>>>(W, wq, scale);
        qgemm<false><<<gemm_grid, 256, 0, stream>>>(x, wq, out, scale, M, N, K);
    } else {
        naive_qgemm<<<dim3(N / 256, M), 256, 0, stream>>>(x, W, out, scale, M);
    }
}

// Round 2
// 408.204 us; speedup vs baseline: 1.1595x; 1.1595x over previous
//
#include <hip/hip_runtime.h>
#include <cstdint>
#include <cstddef>

#define IN_F 4096
#define OUT_F 4096

typedef __attribute__((ext_vector_type(8))) short bf16x8;
typedef __attribute__((ext_vector_type(4))) float f32x4;

__device__ __forceinline__ ushort f32_bf16_rne(float f) {
    uint32_t u = __builtin_bit_cast(uint32_t, f);
    uint32_t r = (u + 0x7FFFu + ((u >> 16) & 1u)) >> 16;
    return (ushort)r;
}

__device__ __forceinline__ void gload_lds16(const void* g, void* l) {
    __builtin_amdgcn_global_load_lds(
        (const __attribute__((address_space(1))) uint32_t*)g,
        (__attribute__((address_space(3))) uint32_t*)l,
        16, 0, 0);
}

// ---------- deterministic |W| reduction (fixed order, no atomics) ----------
__global__ void reduce_abs1(const float* __restrict__ W, float* __restrict__ part) {
    __shared__ float sm[256];
    const int b = blockIdx.x, t = threadIdx.x;
    const float* p = W + (size_t)b * 4096;
    float s = 0.f;
#pragma unroll
    for (int j = 0; j < 16; ++j) s += fabsf(p[t + 256 * j]);
    sm[t] = s;
    __syncthreads();
    for (int w = 128; w > 0; w >>= 1) {
        if (t < w) sm[t] += sm[t + w];
        __syncthreads();
    }
    if (t == 0) part[b] = sm[0];
}

__global__ void reduce_abs2(const float* __restrict__ part, float* __restrict__ scale) {
    __shared__ float sm[256];
    const int t = threadIdx.x;
    float s = 0.f;
#pragma unroll
    for (int j = 0; j < 16; ++j) s += part[t + 256 * j];
    sm[t] = s;
    __syncthreads();
    for (int w = 128; w > 0; w >>= 1) {
        if (t < w) sm[t] += sm[t + w];
        __syncthreads();
    }
    if (t == 0) {
        float m = sm[0] / 16777216.0f;  // mean over 4096*4096
        *scale = fmaxf(m, 1e-8f);
    }
}

// ---------- quantize W -> bf16 {-2,-1,0,1,2} (exact in bf16) ----------
__global__ void quantize_w(const float* __restrict__ W, ushort* __restrict__ wq,
                           const float* __restrict__ scale_p) {
    const int i = blockIdx.x * 256 + threadIdx.x;  // one float4
    const float s = *scale_p;
    float4 v = ((const float4*)W)[i];
    float q0 = fminf(fmaxf(rintf(v.x / s), -2.f), 2.f);
    float q1 = fminf(fmaxf(rintf(v.y / s), -2.f), 2.f);
    float q2 = fminf(fmaxf(rintf(v.z / s), -2.f), 2.f);
    float q3 = fminf(fmaxf(rintf(v.w / s), -2.f), 2.f);
    ushort4 o;
    o.x = f32_bf16_rne(q0); o.y = f32_bf16_rne(q1);
    o.z = f32_bf16_rne(q2); o.w = f32_bf16_rne(q3);
    ((ushort4*)wq)[i] = o;
}

// ---------- cast x -> bf16 (RNE) ----------
__global__ void cast_x(const float* __restrict__ X, ushort* __restrict__ xh) {
    const int i = blockIdx.x * 256 + threadIdx.x;  // one float4
    float4 v = ((const float4*)X)[i];
    ushort4 o;
    o.x = f32_bf16_rne(v.x); o.y = f32_bf16_rne(v.y);
    o.z = f32_bf16_rne(v.z); o.w = f32_bf16_rne(v.w);
    ((ushort4*)xh)[i] = o;
}

// ---------- bf16 MFMA GEMM: C = scale * (A @ Bq^T) ----------
// A: [M][K] (bf16 if ABF16 else fp32), Bq: [N][K] bf16 (K-contiguous).
// 128x128 tile, BK=64, 256 threads = 4 waves (2x2), each wave 64x64 via 4x4
// frags of mfma_f32_16x16x32_bf16.
//
// LDS layout: [128][64] bf16 with XOR swizzle: logical chunk-of-8 c8 of row r
// is stored at chunk position c8 ^ (r&7)  (byte ^= ((r&7)<<4)).
// Staged via global_load_lds with LINEAR dest (rule #21): the swizzle is
// applied by permuting the per-lane GLOBAL source column chunk; ds_read
// applies the same XOR. Breaks the 16-way bank conflict of the 128B row
// stride (lanes 0-15 same bank) down to ~2-way (free, m136).
template <bool ABF16>
__global__ __launch_bounds__(256) void qgemm(const void* __restrict__ Aptr,
                                             const ushort* __restrict__ Bq,
                                             float* __restrict__ C,
                                             const float* __restrict__ scale_p,
                                             int M, int N, int K) {
    __shared__ __align__(16) ushort sA[128 * 64];
    __shared__ __align__(16) ushort sB[128 * 64];

    const int t = threadIdx.x;
    const int lane = t & 63;
    const int w = t >> 6;
    const int wr = w >> 1, wc = w & 1;

    // XCD-bijective block swizzle (grid % 8 == 0 here)
    const int nwg = gridDim.x;
    int wg = blockIdx.x;
    if ((nwg & 7) == 0) wg = (wg & 7) * (nwg >> 3) + (wg >> 3);
    const int MT = M >> 7;
    const int mt = wg % MT;
    const int nt = wg / MT;
    const int m0 = mt * 128, n0 = nt * 128;

    const ushort* Ab = (const ushort*)Aptr;
    const float* Af = (const float*)Aptr;

    f32x4 zero = {0.f, 0.f, 0.f, 0.f};
    f32x4 acc[4][4];
#pragma unroll
    for (int m = 0; m < 4; ++m)
#pragma unroll
        for (int n = 0; n < 4; ++n) acc[m][n] = zero;

    // staging geometry: iteration i, thread t covers LDS elements
    // e = i*2048 + t*8 .. +7  (linear dest = wave-uniform base + lane*16).
    // dest row r = e>>6, dest chunk c8 = (e>>3)&7; global source column
    // chunk = c8 ^ (r&7)  (pre-swizzled source, m173 pattern).
    for (int k0 = 0; k0 < K; k0 += 64) {
#pragma unroll
        for (int i = 0; i < 4; ++i) {
            int e = i * 2048 + t * 8;
            int r = e >> 6, c8 = (e >> 3) & 7;
            int srcc = (c8 ^ (r & 7)) * 8;
            gload_lds16(Bq + (size_t)(n0 + r) * K + (k0 + srcc), &sB[e]);
        }
        if constexpr (ABF16) {
#pragma unroll
            for (int i = 0; i < 4; ++i) {
                int e = i * 2048 + t * 8;
                int r = e >> 6, c8 = (e >> 3) & 7;
                int srcc = (c8 ^ (r & 7)) * 8;
                gload_lds16(Ab + (size_t)(m0 + r) * K + (k0 + srcc), &sA[e]);
            }
        } else {
            // reg-stage fp32 A tile, convert to bf16, swizzled ds_write_b128
#pragma unroll
            for (int i = 0; i < 4; ++i) {
                int e = i * 2048 + t * 8;
                int r = e >> 6, c = e & 63;
                const float* src = Af + (size_t)(m0 + r) * K + (k0 + c);
                float4 v0 = *(const float4*)src;
                float4 v1 = *(const float4*)(src + 4);
                bf16x8 pk;
                pk[0] = (short)f32_bf16_rne(v0.x); pk[1] = (short)f32_bf16_rne(v0.y);
                pk[2] = (short)f32_bf16_rne(v0.z); pk[3] = (short)f32_bf16_rne(v0.w);
                pk[4] = (short)f32_bf16_rne(v1.x); pk[5] = (short)f32_bf16_rne(v1.y);
                pk[6] = (short)f32_bf16_rne(v1.z); pk[7] = (short)f32_bf16_rne(v1.w);
                int byte = (r * 128 + c * 2) ^ ((r & 7) << 4);
                *(bf16x8*)((char*)sA + byte) = pk;
            }
        }
        __syncthreads();

#pragma unroll
        for (int ks = 0; ks < 2; ++ks) {
            const int kk = ks * 32 + ((lane >> 4) << 3);
            bf16x8 afr[4], bfr[4];
#pragma unroll
            for (int m = 0; m < 4; ++m) {
                int r = wr * 64 + m * 16 + (lane & 15);
                int byte = (r * 128 + kk * 2) ^ ((r & 7) << 4);
                afr[m] = *(const bf16x8*)((const char*)sA + byte);
            }
#pragma unroll
            for (int n = 0; n < 4; ++n) {
                int r = wc * 64 + n * 16 + (lane & 15);
                int byte = (r * 128 + kk * 2) ^ ((r & 7) << 4);
                bfr[n] = *(const bf16x8*)((const char*)sB + byte);
            }
#pragma unroll
            for (int m = 0; m < 4; ++m)
#pragma unroll
                for (int n = 0; n < 4; ++n)
                    acc[m][n] = __builtin_amdgcn_mfma_f32_16x16x32_bf16(
                        afr[m], bfr[n], acc[m][n], 0, 0, 0);
        }
        __syncthreads();
    }

    const float s = *scale_p;
#pragma unroll
    for (int m = 0; m < 4; ++m)
#pragma unroll
        for (int n = 0; n < 4; ++n) {
            const int col = n0 + wc * 64 + n * 16 + (lane & 15);
            const int rbase = m0 + wr * 64 + m * 16 + ((lane >> 4) << 2);
#pragma unroll
            for (int j = 0; j < 4; ++j)
                C[(size_t)(rbase + j) * N + col] = s * acc[m][n][j];
        }
}

// ---------- last-resort naive path (only if ws is tiny) ----------
__global__ void naive_qgemm(const float* __restrict__ X, const float* __restrict__ W,
                            float* __restrict__ out, const float* __restrict__ scale_p,
                            int M) {
    const int col = blockIdx.x * 256 + threadIdx.x;
    const int row = blockIdx.y;
    const float s = *scale_p;
    const float inv = 1.0f / s;
    const float* xr = X + (size_t)row * IN_F;
    const float* wrow = W + (size_t)col * IN_F;
    float acc = 0.f;
    for (int k = 0; k < IN_F; ++k) {
        float q = fminf(fmaxf(rintf(wrow[k] * inv), -2.f), 2.f);
        acc += xr[k] * q;
    }
    out[(size_t)row * OUT_F + col] = acc * s;
}

extern "C" void kernel_launch(void* const* d_in, const int* in_sizes, int n_in,
                              void* d_out, int out_size, void* d_ws, size_t ws_size,
                              hipStream_t stream) {
    const float* x = (const float*)d_in[0];
    const float* W = (const float*)d_in[1];
    float* out = (float*)d_out;
    const int M = in_sizes[0] / IN_F;  // 8192
    const int K = IN_F, N = OUT_F;

    char* ws = (char*)d_ws;
    const size_t OFF_PART = 512;
    const size_t OFF_WQ = OFF_PART + 4096 * sizeof(float);        // 16896 (16B-aligned)
    const size_t WQ_BYTES = (size_t)N * K * sizeof(ushort);       // 33.5 MB
    const size_t OFF_XH = OFF_WQ + WQ_BYTES;
    const size_t XH_BYTES = (size_t)M * K * sizeof(ushort);       // 67 MB
    float* scale = (float*)(ws + 0);
    float* part = (float*)(ws + OFF_PART);
    ushort* wq = (ushort*)(ws + OFF_WQ);
    ushort* xh = (ushort*)(ws + OFF_XH);

    if (ws_size < OFF_WQ) return;

    reduce_abs1<<<4096, 256, 0, stream>>>(W, part);
    reduce_abs2<<<1, 256, 0, stream>>>(part, scale);

    const int gemm_grid = (M / 128) * (N / 128);  // 2048

    if (ws_size >= OFF_XH + XH_BYTES) {
        quantize_w<<<(N * K / 4) / 256, 256, 0, stream>>>(W, wq, scale);
        cast_x<<<(M * K / 4) / 256, 256, 0, stream>>>(x, xh);
        qgemm<true><<<gemm_grid, 256, 0, stream>>>(xh, wq, out, scale, M, N, K);
    } else if (ws_size >= OFF_WQ + WQ_BYTES) {
        quantize_w<<<(N * K / 4) / 256, 256, 0, stream>>>(W, wq, scale);
        qgemm<false><<<gemm_grid, 256, 0, stream>>>(x, wq, out, scale, M, N, K);
    } else {
        naive_qgemm<<<dim3(N / 256, M), 256, 0, stream>>>(x, W, out, scale, M);
    }
}

// Round 3
// 338.354 us; speedup vs baseline: 1.3989x; 1.2064x over previous
//
#include <hip/hip_runtime.h>
#include <cstdint>
#include <cstddef>

#define IN_F 4096
#define OUT_F 4096

typedef __attribute__((ext_vector_type(8))) short bf16x8;
typedef __attribute__((ext_vector_type(4))) float f32x4;

__device__ __forceinline__ ushort f32_bf16_rne(float f) {
    uint32_t u = __builtin_bit_cast(uint32_t, f);
    uint32_t r = (u + 0x7FFFu + ((u >> 16) & 1u)) >> 16;
    return (ushort)r;
}

__device__ __forceinline__ void gload_lds16(const void* g, void* l) {
    __builtin_amdgcn_global_load_lds(
        (const __attribute__((address_space(1))) uint32_t*)g,
        (__attribute__((address_space(3))) uint32_t*)l,
        16, 0, 0);
}

// barrier with compiler+scheduler fences: raw s_barrier has no memory
// semantics for hipcc (rule #18 family) — pin all motion across it.
__device__ __forceinline__ void fenced_barrier() {
    asm volatile("" ::: "memory");
    __builtin_amdgcn_sched_barrier(0);
    __builtin_amdgcn_s_barrier();
    __builtin_amdgcn_sched_barrier(0);
    asm volatile("" ::: "memory");
}

// ---------- deterministic |W| reduction (fixed order, no atomics) ----------
__global__ void reduce_abs1(const float* __restrict__ W, float* __restrict__ part) {
    __shared__ float sm[256];
    const int b = blockIdx.x, t = threadIdx.x;
    const float* p = W + (size_t)b * 4096;
    float s = 0.f;
#pragma unroll
    for (int j = 0; j < 16; ++j) s += fabsf(p[t + 256 * j]);
    sm[t] = s;
    __syncthreads();
    for (int w = 128; w > 0; w >>= 1) {
        if (t < w) sm[t] += sm[t + w];
        __syncthreads();
    }
    if (t == 0) part[b] = sm[0];
}

__global__ void reduce_abs2(const float* __restrict__ part, float* __restrict__ scale) {
    __shared__ float sm[256];
    const int t = threadIdx.x;
    float s = 0.f;
#pragma unroll
    for (int j = 0; j < 16; ++j) s += part[t + 256 * j];
    sm[t] = s;
    __syncthreads();
    for (int w = 128; w > 0; w >>= 1) {
        if (t < w) sm[t] += sm[t + w];
        __syncthreads();
    }
    if (t == 0) {
        float m = sm[0] / 16777216.0f;
        *scale = fmaxf(m, 1e-8f);
    }
}

// ---------- quantize W -> bf16 {-2,-1,0,1,2} (exact in bf16) ----------
__global__ void quantize_w(const float* __restrict__ W, ushort* __restrict__ wq,
                           const float* __restrict__ scale_p) {
    const int i = blockIdx.x * 256 + threadIdx.x;
    const float s = *scale_p;
    float4 v = ((const float4*)W)[i];
    float q0 = fminf(fmaxf(rintf(v.x / s), -2.f), 2.f);
    float q1 = fminf(fmaxf(rintf(v.y / s), -2.f), 2.f);
    float q2 = fminf(fmaxf(rintf(v.z / s), -2.f), 2.f);
    float q3 = fminf(fmaxf(rintf(v.w / s), -2.f), 2.f);
    ushort4 o;
    o.x = f32_bf16_rne(q0); o.y = f32_bf16_rne(q1);
    o.z = f32_bf16_rne(q2); o.w = f32_bf16_rne(q3);
    ((ushort4*)wq)[i] = o;
}

// ---------- cast x -> bf16 (RNE) ----------
__global__ void cast_x(const float* __restrict__ X, ushort* __restrict__ xh) {
    const int i = blockIdx.x * 256 + threadIdx.x;
    float4 v = ((const float4*)X)[i];
    ushort4 o;
    o.x = f32_bf16_rne(v.x); o.y = f32_bf16_rne(v.y);
    o.z = f32_bf16_rne(v.z); o.w = f32_bf16_rne(v.w);
    ((ushort4*)xh)[i] = o;
}

// ================= 256x256 8-phase GEMM (m201-style template) =================
// C = scale * (A @ B^T).  A:[M][K] bf16, B:[N][K] bf16 (both K-contiguous).
// 512 threads = 8 waves (2M x 4N); per-wave output 128x64 (acc[8][4] f32x4).
// LDS 128 KiB: 2 K-tile buffers, each {A half0, A half1, B half0, B half1},
// half-tile = 128x64 bf16 = 16 KiB, XOR-swizzled (byte ^= (r&7)<<4) via
// pre-swizzled global source + swizzled ds_read (both-sides, rule #21).
//
// Per K-tile: 4 phases, each {ds_reads; stage 1 half-tile (2 gload_lds16);
// barrier; setprio1; 16 MFMA; setprio0; barrier}. Stage stream 3 half-tiles
// ahead; vmcnt(6) at K-tile boundaries (vmcnt(0) only at the final drain).
// Region discipline (write-after-read safety, barrier-separated):
//   reads:  B (all frags) in P1; A mq0 in P1; A mq1 in P2.
//   overwrites (stream order B0,B1,A0,A1): B0@P2, B1@P3, A0@P4, A1@next-P1.
#define BK 64
#define HT_BYTES 16384
#define BUF_BYTES 65536

__global__ __launch_bounds__(512, 2) void qgemm256(
        const ushort* __restrict__ Ab, const ushort* __restrict__ Bq,
        float* __restrict__ C, const float* __restrict__ scale_p,
        int M, int N, int K) {
    extern __shared__ __align__(16) char smem[];

    const int t = threadIdx.x;
    const int lane = t & 63;
    const int w = t >> 6;
    const int wr = w >> 2;   // 0..1 (M)
    const int wc = w & 3;    // 0..3 (N)
    const int bh = wc >> 1;  // B half

    // XCD-bijective block swizzle (512 % 8 == 0)
    const int nwg = gridDim.x;
    int wg = blockIdx.x;
    if ((nwg & 7) == 0) wg = (wg & 7) * (nwg >> 3) + (wg >> 3);
    const int MT = M >> 8;
    const int m0 = (wg % MT) << 8;
    const int n0 = (wg / MT) << 8;

    const int NT = K / BK;    // 64 K-tiles
    const int NS = NT * 4;    // 256 half-tile streams

    // per-lane ds_read byte offsets within a half-tile (add m/n*2048 above)
    int pre[2];
#pragma unroll
    for (int ks = 0; ks < 2; ++ks)
        pre[ks] = (lane & 15) * 128 +
                  (((ks * 64) + ((lane >> 4) * 16)) ^ ((lane & 7) << 4));

    auto do_stage = [&](int s) {
        if (s >= NS) return;
        const int kt = s >> 2, h = s & 3;
        const int k0 = kt * BK;
        char* region;
        const ushort* gsrc;
        if (h < 2) {  // B half h
            region = smem + (kt & 1) * BUF_BYTES + 32768 + h * HT_BYTES;
            gsrc = Bq + (size_t)(n0 + h * 128) * K + k0;
        } else {      // A half h-2
            region = smem + (kt & 1) * BUF_BYTES + (h - 2) * HT_BYTES;
            gsrc = Ab + (size_t)(m0 + (h - 2) * 128) * K + k0;
        }
#pragma unroll
        for (int j = 0; j < 2; ++j) {
            int e = j * 4096 + t * 8;          // element in 128x64 half-tile
            int r = e >> 6, c8 = (e >> 3) & 7;
            int srcc = (c8 ^ (r & 7)) * 8;     // pre-swizzled global column
            gload_lds16(gsrc + (size_t)r * K + srcc, region + e * 2);
        }
    };

    f32x4 acc[8][4];
#pragma unroll
    for (int m = 0; m < 8; ++m)
#pragma unroll
        for (int n = 0; n < 4; ++n) acc[m][n] = (f32x4){0.f, 0.f, 0.f, 0.f};

    // ---- prologue: K-tile 0 fully + 3 halves of K-tile 1 ----
    do_stage(0); do_stage(1); do_stage(2); do_stage(3);
    asm volatile("s_waitcnt vmcnt(4)");
    do_stage(4); do_stage(5); do_stage(6);
    asm volatile("s_waitcnt vmcnt(6)");  // K-tile 0 landed, 3 in flight
    fenced_barrier();

    for (int kt = 0; kt < NT; ++kt) {
        const char* aB = smem + (kt & 1) * BUF_BYTES + wr * HT_BYTES;
        const char* bB = smem + (kt & 1) * BUF_BYTES + 32768 + bh * HT_BYTES +
                         (wc & 1) * 8192;
        const int sbase = 7 + kt * 4;

        bf16x8 bfr[4][2], a0[4][2], a1[4][2];

        // ---------- phase 1: read B(all) + A mq0; MFMA mq0 x nq0 ----------
#pragma unroll
        for (int n = 0; n < 4; ++n)
#pragma unroll
            for (int ks = 0; ks < 2; ++ks)
                bfr[n][ks] = *(const bf16x8*)(bB + n * 2048 + pre[ks]);
#pragma unroll
        for (int m = 0; m < 4; ++m)
#pragma unroll
            for (int ks = 0; ks < 2; ++ks)
                a0[m][ks] = *(const bf16x8*)(aB + m * 2048 + pre[ks]);
        do_stage(sbase + 0);
        fenced_barrier();
        __builtin_amdgcn_s_setprio(1);
#pragma unroll
        for (int m = 0; m < 4; ++m)
#pragma unroll
            for (int n = 0; n < 2; ++n)
#pragma unroll
                for (int ks = 0; ks < 2; ++ks)
                    acc[m][n] = __builtin_amdgcn_mfma_f32_16x16x32_bf16(
                        a0[m][ks], bfr[n][ks], acc[m][n], 0, 0, 0);
        __builtin_amdgcn_s_setprio(0);
        fenced_barrier();

        // ---------- phase 2: read A mq1; MFMA mq0 x nq1 ----------
#pragma unroll
        for (int m = 0; m < 4; ++m)
#pragma unroll
            for (int ks = 0; ks < 2; ++ks)
                a1[m][ks] = *(const bf16x8*)(aB + (m + 4) * 2048 + pre[ks]);
        do_stage(sbase + 1);
        fenced_barrier();
        __builtin_amdgcn_s_setprio(1);
#pragma unroll
        for (int m = 0; m < 4; ++m)
#pragma unroll
            for (int n = 2; n < 4; ++n)
#pragma unroll
                for (int ks = 0; ks < 2; ++ks)
                    acc[m][n] = __builtin_amdgcn_mfma_f32_16x16x32_bf16(
                        a0[m][ks], bfr[n][ks], acc[m][n], 0, 0, 0);
        __builtin_amdgcn_s_setprio(0);
        fenced_barrier();

        // ---------- phase 3: MFMA mq1 x nq0 ----------
        do_stage(sbase + 2);
        fenced_barrier();
        __builtin_amdgcn_s_setprio(1);
#pragma unroll
        for (int m = 0; m < 4; ++m)
#pragma unroll
            for (int n = 0; n < 2; ++n)
#pragma unroll
                for (int ks = 0; ks < 2; ++ks)
                    acc[m + 4][n] = __builtin_amdgcn_mfma_f32_16x16x32_bf16(
                        a1[m][ks], bfr[n][ks], acc[m + 4][n], 0, 0, 0);
        __builtin_amdgcn_s_setprio(0);
        fenced_barrier();

        // ---------- phase 4: MFMA mq1 x nq1; boundary vmcnt ----------
        do_stage(sbase + 3);
        fenced_barrier();
        __builtin_amdgcn_s_setprio(1);
#pragma unroll
        for (int m = 0; m < 4; ++m)
#pragma unroll
            for (int n = 2; n < 4; ++n)
#pragma unroll
                for (int ks = 0; ks < 2; ++ks)
                    acc[m + 4][n] = __builtin_amdgcn_mfma_f32_16x16x32_bf16(
                        a1[m][ks], bfr[n][ks], acc[m + 4][n], 0, 0, 0);
        __builtin_amdgcn_s_setprio(0);
        if (kt < NT - 2) {
            asm volatile("s_waitcnt vmcnt(6)");  // next K-tile landed, 3 in flight
        } else if (kt == NT - 2) {
            asm volatile("s_waitcnt vmcnt(0)");  // final drain
        }
        fenced_barrier();
    }

    const float s = *scale_p;
#pragma unroll
    for (int m = 0; m < 8; ++m)
#pragma unroll
        for (int n = 0; n < 4; ++n) {
            const int col = n0 + wc * 64 + n * 16 + (lane & 15);
            const int rbase = m0 + wr * 128 + m * 16 + ((lane >> 4) << 2);
#pragma unroll
            for (int j = 0; j < 4; ++j)
                C[(size_t)(rbase + j) * N + col] = s * acc[m][n][j];
        }
}

// ---------- 128^2 fallback (validated round 2) ----------
template <bool ABF16>
__global__ __launch_bounds__(256) void qgemm(const void* __restrict__ Aptr,
                                             const ushort* __restrict__ Bq,
                                             float* __restrict__ C,
                                             const float* __restrict__ scale_p,
                                             int M, int N, int K) {
    __shared__ __align__(16) ushort sA[128 * 64];
    __shared__ __align__(16) ushort sB[128 * 64];

    const int t = threadIdx.x;
    const int lane = t & 63;
    const int w = t >> 6;
    const int wr = w >> 1, wc = w & 1;

    const int nwg = gridDim.x;
    int wg = blockIdx.x;
    if ((nwg & 7) == 0) wg = (wg & 7) * (nwg >> 3) + (wg >> 3);
    const int MT = M >> 7;
    const int mt = wg % MT;
    const int nt = wg / MT;
    const int m0 = mt * 128, n0 = nt * 128;

    const ushort* Ab = (const ushort*)Aptr;
    const float* Af = (const float*)Aptr;

    f32x4 zero = {0.f, 0.f, 0.f, 0.f};
    f32x4 acc[4][4];
#pragma unroll
    for (int m = 0; m < 4; ++m)
#pragma unroll
        for (int n = 0; n < 4; ++n) acc[m][n] = zero;

    for (int k0 = 0; k0 < K; k0 += 64) {
#pragma unroll
        for (int i = 0; i < 4; ++i) {
            int e = i * 2048 + t * 8;
            int r = e >> 6, c8 = (e >> 3) & 7;
            int srcc = (c8 ^ (r & 7)) * 8;
            gload_lds16(Bq + (size_t)(n0 + r) * K + (k0 + srcc), &sB[e]);
        }
        if constexpr (ABF16) {
#pragma unroll
            for (int i = 0; i < 4; ++i) {
                int e = i * 2048 + t * 8;
                int r = e >> 6, c8 = (e >> 3) & 7;
                int srcc = (c8 ^ (r & 7)) * 8;
                gload_lds16(Ab + (size_t)(m0 + r) * K + (k0 + srcc), &sA[e]);
            }
        } else {
#pragma unroll
            for (int i = 0; i < 4; ++i) {
                int e = i * 2048 + t * 8;
                int r = e >> 6, c = e & 63;
                const float* src = Af + (size_t)(m0 + r) * K + (k0 + c);
                float4 v0 = *(const float4*)src;
                float4 v1 = *(const float4*)(src + 4);
                bf16x8 pk;
                pk[0] = (short)f32_bf16_rne(v0.x); pk[1] = (short)f32_bf16_rne(v0.y);
                pk[2] = (short)f32_bf16_rne(v0.z); pk[3] = (short)f32_bf16_rne(v0.w);
                pk[4] = (short)f32_bf16_rne(v1.x); pk[5] = (short)f32_bf16_rne(v1.y);
                pk[6] = (short)f32_bf16_rne(v1.z); pk[7] = (short)f32_bf16_rne(v1.w);
                int byte = (r * 128 + c * 2) ^ ((r & 7) << 4);
                *(bf16x8*)((char*)sA + byte) = pk;
            }
        }
        __syncthreads();

#pragma unroll
        for (int ks = 0; ks < 2; ++ks) {
            const int kk = ks * 32 + ((lane >> 4) << 3);
            bf16x8 afr[4], bfr[4];
#pragma unroll
            for (int m = 0; m < 4; ++m) {
                int r = wr * 64 + m * 16 + (lane & 15);
                int byte = (r * 128 + kk * 2) ^ ((r & 7) << 4);
                afr[m] = *(const bf16x8*)((const char*)sA + byte);
            }
#pragma unroll
            for (int n = 0; n < 4; ++n) {
                int r = wc * 64 + n * 16 + (lane & 15);
                int byte = (r * 128 + kk * 2) ^ ((r & 7) << 4);
                bfr[n] = *(const bf16x8*)((const char*)sB + byte);
            }
#pragma unroll
            for (int m = 0; m < 4; ++m)
#pragma unroll
                for (int n = 0; n < 4; ++n)
                    acc[m][n] = __builtin_amdgcn_mfma_f32_16x16x32_bf16(
                        afr[m], bfr[n], acc[m][n], 0, 0, 0);
        }
        __syncthreads();
    }

    const float s = *scale_p;
#pragma unroll
    for (int m = 0; m < 4; ++m)
#pragma unroll
        for (int n = 0; n < 4; ++n) {
            const int col = n0 + wc * 64 + n * 16 + (lane & 15);
            const int rbase = m0 + wr * 64 + m * 16 + ((lane >> 4) << 2);
#pragma unroll
            for (int j = 0; j < 4; ++j)
                C[(size_t)(rbase + j) * N + col] = s * acc[m][n][j];
        }
}

// ---------- last-resort naive path ----------
__global__ void naive_qgemm(const float* __restrict__ X, const float* __restrict__ W,
                            float* __restrict__ out, const float* __restrict__ scale_p,
                            int M) {
    const int col = blockIdx.x * 256 + threadIdx.x;
    const int row = blockIdx.y;
    const float s = *scale_p;
    const float inv = 1.0f / s;
    const float* xr = X + (size_t)row * IN_F;
    const float* wrow = W + (size_t)col * IN_F;
    float acc = 0.f;
    for (int k = 0; k < IN_F; ++k) {
        float q = fminf(fmaxf(rintf(wrow[k] * inv), -2.f), 2.f);
        acc += xr[k] * q;
    }
    out[(size_t)row * OUT_F + col] = acc * s;
}

extern "C" void kernel_launch(void* const* d_in, const int* in_sizes, int n_in,
                              void* d_out, int out_size, void* d_ws, size_t ws_size,
                              hipStream_t stream) {
    const float* x = (const float*)d_in[0];
    const float* W = (const float*)d_in[1];
    float* out = (float*)d_out;
    const int M = in_sizes[0] / IN_F;  // 8192
    const int K = IN_F, N = OUT_F;

    char* ws = (char*)d_ws;
    const size_t OFF_PART = 512;
    const size_t OFF_WQ = OFF_PART + 4096 * sizeof(float);
    const size_t WQ_BYTES = (size_t)N * K * sizeof(ushort);
    const size_t OFF_XH = OFF_WQ + WQ_BYTES;
    const size_t XH_BYTES = (size_t)M * K * sizeof(ushort);
    float* scale = (float*)(ws + 0);
    float* part = (float*)(ws + OFF_PART);
    ushort* wq = (ushort*)(ws + OFF_WQ);
    ushort* xh = (ushort*)(ws + OFF_XH);

    if (ws_size < OFF_WQ) return;

    reduce_abs1<<<4096, 256, 0, stream>>>(W, part);
    reduce_abs2<<<1, 256, 0, stream>>>(part, scale);

    if (ws_size >= OFF_XH + XH_BYTES && (M % 256) == 0 && (N % 256) == 0) {
        quantize_w<<<(N * K / 4) / 256, 256, 0, stream>>>(W, wq, scale);
        cast_x<<<(M * K / 4) / 256, 256, 0, stream>>>(x, xh);
        (void)hipFuncSetAttribute((const void*)qgemm256,
                                  hipFuncAttributeMaxDynamicSharedMemorySize,
                                  131072);
        qgemm256<<<(M / 256) * (N / 256), 512, 131072, stream>>>(
            xh, wq, out, scale, M, N, K);
    } else if (ws_size >= OFF_XH + XH_BYTES) {
        quantize_w<<<(N * K / 4) / 256, 256, 0, stream>>>(W, wq, scale);
        cast_x<<<(M * K / 4) / 256, 256, 0, stream>>>(x, xh);
        qgemm<true><<<(M / 128) * (N / 128), 256, 0, stream>>>(xh, wq, out, scale, M, N, K);
    } else if (ws_size >= OFF_WQ + WQ_BYTES) {
        quantize_w<<<(N * K / 4) / 256, 256, 0, stream>>>(W, wq, scale);
        qgemm<false><<<(M / 128) * (N / 128), 256, 0, stream>>>(x, wq, out, scale, M, N, K);
    } else {
        naive_qgemm<<<dim3(N / 256, M), 256, 0, stream>>>(x, W, out, scale, M);
    }
}

// Round 4
// 337.106 us; speedup vs baseline: 1.4041x; 1.0037x over previous
//
#include <hip/hip_runtime.h>
#include <cstdint>
#include <cstddef>

#define IN_F 4096
#define OUT_F 4096

typedef __attribute__((ext_vector_type(8))) short bf16x8;
typedef __attribute__((ext_vector_type(4))) float f32x4;

__device__ __forceinline__ ushort f32_bf16_rne(float f) {
    uint32_t u = __builtin_bit_cast(uint32_t, f);
    uint32_t r = (u + 0x7FFFu + ((u >> 16) & 1u)) >> 16;
    return (ushort)r;
}

__device__ __forceinline__ void gload_lds16(const void* g, void* l) {
    __builtin_amdgcn_global_load_lds(
        (const __attribute__((address_space(1))) uint32_t*)g,
        (__attribute__((address_space(3))) uint32_t*)l,
        16, 0, 0);
}

// Light barrier: memory clobber orders LDS/global memory ops across it
// (cross-wave buffer hazard) WITHOUT sched_barrier(0) pinning of VALU/MFMA
// (m141: full pinning -42%). MFMA operands are compiler-visible ds_read
// results -> register deps order them; no rule-#18 hazard here.
__device__ __forceinline__ void bar() {
    asm volatile("s_barrier" ::: "memory");
}

// ---------- deterministic |W| reduction (fixed order, no atomics) ----------
__global__ void reduce_abs1(const float* __restrict__ W, float* __restrict__ part) {
    __shared__ float sm[256];
    const int b = blockIdx.x, t = threadIdx.x;
    const float* p = W + (size_t)b * 4096;
    float s = 0.f;
#pragma unroll
    for (int j = 0; j < 16; ++j) s += fabsf(p[t + 256 * j]);
    sm[t] = s;
    __syncthreads();
    for (int w = 128; w > 0; w >>= 1) {
        if (t < w) sm[t] += sm[t + w];
        __syncthreads();
    }
    if (t == 0) part[b] = sm[0];
}

__global__ void reduce_abs2(const float* __restrict__ part, float* __restrict__ scale) {
    __shared__ float sm[256];
    const int t = threadIdx.x;
    float s = 0.f;
#pragma unroll
    for (int j = 0; j < 16; ++j) s += part[t + 256 * j];
    sm[t] = s;
    __syncthreads();
    for (int w = 128; w > 0; w >>= 1) {
        if (t < w) sm[t] += sm[t + w];
        __syncthreads();
    }
    if (t == 0) {
        float m = sm[0] / 16777216.0f;
        *scale = fmaxf(m, 1e-8f);
    }
}

// ---------- quantize W -> bf16 {-2,-1,0,1,2} (exact in bf16) ----------
__global__ void quantize_w(const float* __restrict__ W, ushort* __restrict__ wq,
                           const float* __restrict__ scale_p) {
    const int i = blockIdx.x * 256 + threadIdx.x;
    const float s = *scale_p;
    float4 v = ((const float4*)W)[i];
    float q0 = fminf(fmaxf(rintf(v.x / s), -2.f), 2.f);
    float q1 = fminf(fmaxf(rintf(v.y / s), -2.f), 2.f);
    float q2 = fminf(fmaxf(rintf(v.z / s), -2.f), 2.f);
    float q3 = fminf(fmaxf(rintf(v.w / s), -2.f), 2.f);
    ushort4 o;
    o.x = f32_bf16_rne(q0); o.y = f32_bf16_rne(q1);
    o.z = f32_bf16_rne(q2); o.w = f32_bf16_rne(q3);
    ((ushort4*)wq)[i] = o;
}

// ---------- cast x -> bf16 (RNE) ----------
__global__ void cast_x(const float* __restrict__ X, ushort* __restrict__ xh) {
    const int i = blockIdx.x * 256 + threadIdx.x;
    float4 v = ((const float4*)X)[i];
    ushort4 o;
    o.x = f32_bf16_rne(v.x); o.y = f32_bf16_rne(v.y);
    o.z = f32_bf16_rne(v.z); o.w = f32_bf16_rne(v.w);
    ((ushort4*)xh)[i] = o;
}

// ================= 256x256 8-phase GEMM (m201-style template) =================
// C = scale * (A @ B^T).  A:[M][K] bf16, B:[N][K] bf16 (both K-contiguous).
// 512 threads = 8 waves (2M x 4N); per-wave output 128x64 (acc[8][4] f32x4).
// LDS 128 KiB: 2 K-tile buffers x {A0,A1,B0,B1} 16 KiB half-tiles (128x64),
// XOR-swizzled (byte ^= (r&7)<<4) via pre-swizzled global source + swizzled
// ds_read (both-sides-or-neither, rule #21).
//
// Balanced 4-phase schedule per K-tile (reads 12/8/4/0), stage stream order
// A0,A1,B0,B1 so each region's overwrite-issue is >=1 barrier after its
// reads are lgkm-drained (in-order lgkm + same-phase MFMA consumption):
//   P1: read bfr[0..1]+a0; stage(kt+1 B1); bar; MFMA Q00(a0 x n01); bar
//   P2: read a1;           stage(kt+2 A0); bar; MFMA Q10(a1 x n01); bar
//   P3: read bfr[2..3];    stage(kt+2 A1); bar; MFMA Q01(a0 x n23); bar
//   P4:                    stage(kt+2 B0); bar; MFMA Q11(a1 x n23); vmcnt; bar
// vmcnt(6) only at K-tile boundary (3 half-tiles in flight); vmcnt(0) only
// at the final drain (kt == NT-2).
#define BK 64
#define HT_BYTES 16384
#define BUF_BYTES 65536

__global__ __launch_bounds__(512, 2) void qgemm256(
        const ushort* __restrict__ Ab, const ushort* __restrict__ Bq,
        float* __restrict__ C, const float* __restrict__ scale_p,
        int M, int N, int K) {
    extern __shared__ __align__(16) char smem[];

    const int t = threadIdx.x;
    const int lane = t & 63;
    const int w = t >> 6;
    const int wr = w >> 2;   // 0..1 (M half)
    const int wc = w & 3;    // 0..3 (N quarter)
    const int bh = wc >> 1;  // B half

    // XCD-bijective block swizzle (grid = 512, 512 % 8 == 0)
    const int nwg = gridDim.x;
    int wg = blockIdx.x;
    if ((nwg & 7) == 0) wg = (wg & 7) * (nwg >> 3) + (wg >> 3);
    const int MT = M >> 8;
    const int m0 = (wg % MT) << 8;
    const int n0 = (wg / MT) << 8;

    const int NT = K / BK;    // K-tiles
    const int NS = NT * 4;    // half-tile stream length

    // per-lane ds_read byte offsets within a half-tile (add frag*2048 above)
    int pre[2];
#pragma unroll
    for (int ks = 0; ks < 2; ++ks)
        pre[ks] = (lane & 15) * 128 +
                  (((ks * 64) + ((lane >> 4) * 16)) ^ ((lane & 7) << 4));

    // stream s: kt = s>>2, h = s&3; h: 0->A0, 1->A1, 2->B0, 3->B1
    auto do_stage = [&](int s) {
        if (s >= NS) return;
        const int kt = s >> 2, h = s & 3;
        const int k0 = kt * BK;
        char* bufbase = smem + (kt & 1) * BUF_BYTES;
        char* region;
        const ushort* gsrc;
        if (h < 2) {
            region = bufbase + h * HT_BYTES;
            gsrc = Ab + (size_t)(m0 + h * 128) * K + k0;
        } else {
            region = bufbase + 32768 + (h - 2) * HT_BYTES;
            gsrc = Bq + (size_t)(n0 + (h - 2) * 128) * K + k0;
        }
#pragma unroll
        for (int j = 0; j < 2; ++j) {
            int e = j * 4096 + t * 8;          // element in 128x64 half-tile
            int r = e >> 6, c8 = (e >> 3) & 7;
            int srcc = (c8 ^ (r & 7)) * 8;     // pre-swizzled global column
            gload_lds16(gsrc + (size_t)r * K + srcc, region + e * 2);
        }
    };

    f32x4 acc[8][4];
#pragma unroll
    for (int m = 0; m < 8; ++m)
#pragma unroll
        for (int n = 0; n < 4; ++n) acc[m][n] = (f32x4){0.f, 0.f, 0.f, 0.f};

    // ---- prologue: tile 0 fully + 3 halves of tile 1 (14 instr in flight) ----
    do_stage(0); do_stage(1); do_stage(2); do_stage(3);
    do_stage(4); do_stage(5); do_stage(6);
    asm volatile("s_waitcnt vmcnt(6)" ::: "memory");  // tile 0 landed
    bar();

    for (int kt = 0; kt < NT; ++kt) {
        const char* aB = smem + (kt & 1) * BUF_BYTES + wr * HT_BYTES;
        const char* bB = smem + (kt & 1) * BUF_BYTES + 32768 + bh * HT_BYTES +
                         (wc & 1) * 8192;
        const int sbase = 7 + kt * 4;

        bf16x8 bfr[4][2], a0[4][2], a1[4][2];

        // -------- P1: read bfr[0..1] + a0; MFMA Q00 --------
#pragma unroll
        for (int n = 0; n < 2; ++n)
#pragma unroll
            for (int ks = 0; ks < 2; ++ks)
                bfr[n][ks] = *(const bf16x8*)(bB + n * 2048 + pre[ks]);
#pragma unroll
        for (int m = 0; m < 4; ++m)
#pragma unroll
            for (int ks = 0; ks < 2; ++ks)
                a0[m][ks] = *(const bf16x8*)(aB + m * 2048 + pre[ks]);
        do_stage(sbase + 0);  // tile kt+1 B1 (other buffer)
        bar();
        __builtin_amdgcn_s_setprio(1);
#pragma unroll
        for (int m = 0; m < 4; ++m)
#pragma unroll
            for (int n = 0; n < 2; ++n)
#pragma unroll
                for (int ks = 0; ks < 2; ++ks)
                    acc[m][n] = __builtin_amdgcn_mfma_f32_16x16x32_bf16(
                        a0[m][ks], bfr[n][ks], acc[m][n], 0, 0, 0);
        __builtin_amdgcn_s_setprio(0);
        bar();

        // -------- P2: read a1; MFMA Q10 --------
#pragma unroll
        for (int m = 0; m < 4; ++m)
#pragma unroll
            for (int ks = 0; ks < 2; ++ks)
                a1[m][ks] = *(const bf16x8*)(aB + (m + 4) * 2048 + pre[ks]);
        do_stage(sbase + 1);  // tile kt+2 A0 (current buffer, reads done P1)
        bar();
        __builtin_amdgcn_s_setprio(1);
#pragma unroll
        for (int m = 0; m < 4; ++m)
#pragma unroll
            for (int n = 0; n < 2; ++n)
#pragma unroll
                for (int ks = 0; ks < 2; ++ks)
                    acc[m + 4][n] = __builtin_amdgcn_mfma_f32_16x16x32_bf16(
                        a1[m][ks], bfr[n][ks], acc[m + 4][n], 0, 0, 0);
        __builtin_amdgcn_s_setprio(0);
        bar();

        // -------- P3: read bfr[2..3]; MFMA Q01 --------
#pragma unroll
        for (int n = 2; n < 4; ++n)
#pragma unroll
            for (int ks = 0; ks < 2; ++ks)
                bfr[n][ks] = *(const bf16x8*)(bB + n * 2048 + pre[ks]);
        do_stage(sbase + 2);  // tile kt+2 A1 (current buffer, reads done P2)
        bar();
        __builtin_amdgcn_s_setprio(1);
#pragma unroll
        for (int m = 0; m < 4; ++m)
#pragma unroll
            for (int n = 2; n < 4; ++n)
#pragma unroll
                for (int ks = 0; ks < 2; ++ks)
                    acc[m][n] = __builtin_amdgcn_mfma_f32_16x16x32_bf16(
                        a0[m][ks], bfr[n][ks], acc[m][n], 0, 0, 0);
        __builtin_amdgcn_s_setprio(0);
        bar();

        // -------- P4: pure compute; MFMA Q11; boundary vmcnt --------
        do_stage(sbase + 3);  // tile kt+2 B0 (current buffer, reads done P1/P3)
        bar();
        __builtin_amdgcn_s_setprio(1);
#pragma unroll
        for (int m = 0; m < 4; ++m)
#pragma unroll
            for (int n = 2; n < 4; ++n)
#pragma unroll
                for (int ks = 0; ks < 2; ++ks)
                    acc[m + 4][n] = __builtin_amdgcn_mfma_f32_16x16x32_bf16(
                        a1[m][ks], bfr[n][ks], acc[m + 4][n], 0, 0, 0);
        __builtin_amdgcn_s_setprio(0);
        if (kt < NT - 2) {
            asm volatile("s_waitcnt vmcnt(6)" ::: "memory");  // next tile landed
        } else if (kt == NT - 2) {
            asm volatile("s_waitcnt vmcnt(0)" ::: "memory");  // final drain
        }
        bar();
    }

    const float s = *scale_p;
#pragma unroll
    for (int m = 0; m < 8; ++m)
#pragma unroll
        for (int n = 0; n < 4; ++n) {
            const int col = n0 + wc * 64 + n * 16 + (lane & 15);
            const int rbase = m0 + wr * 128 + m * 16 + ((lane >> 4) << 2);
#pragma unroll
            for (int j = 0; j < 4; ++j)
                C[(size_t)(rbase + j) * N + col] = s * acc[m][n][j];
        }
}

// ---------- 128^2 fallback (validated round 2) ----------
template <bool ABF16>
__global__ __launch_bounds__(256) void qgemm(const void* __restrict__ Aptr,
                                             const ushort* __restrict__ Bq,
                                             float* __restrict__ C,
                                             const float* __restrict__ scale_p,
                                             int M, int N, int K) {
    __shared__ __align__(16) ushort sA[128 * 64];
    __shared__ __align__(16) ushort sB[128 * 64];

    const int t = threadIdx.x;
    const int lane = t & 63;
    const int w = t >> 6;
    const int wr = w >> 1, wc = w & 1;

    const int nwg = gridDim.x;
    int wg = blockIdx.x;
    if ((nwg & 7) == 0) wg = (wg & 7) * (nwg >> 3) + (wg >> 3);
    const int MT = M >> 7;
    const int mt = wg % MT;
    const int nt = wg / MT;
    const int m0 = mt * 128, n0 = nt * 128;

    const ushort* Ab = (const ushort*)Aptr;
    const float* Af = (const float*)Aptr;

    f32x4 zero = {0.f, 0.f, 0.f, 0.f};
    f32x4 acc[4][4];
#pragma unroll
    for (int m = 0; m < 4; ++m)
#pragma unroll
        for (int n = 0; n < 4; ++n) acc[m][n] = zero;

    for (int k0 = 0; k0 < K; k0 += 64) {
#pragma unroll
        for (int i = 0; i < 4; ++i) {
            int e = i * 2048 + t * 8;
            int r = e >> 6, c8 = (e >> 3) & 7;
            int srcc = (c8 ^ (r & 7)) * 8;
            gload_lds16(Bq + (size_t)(n0 + r) * K + (k0 + srcc), &sB[e]);
        }
        if constexpr (ABF16) {
#pragma unroll
            for (int i = 0; i < 4; ++i) {
                int e = i * 2048 + t * 8;
                int r = e >> 6, c8 = (e >> 3) & 7;
                int srcc = (c8 ^ (r & 7)) * 8;
                gload_lds16(Ab + (size_t)(m0 + r) * K + (k0 + srcc), &sA[e]);
            }
        } else {
#pragma unroll
            for (int i = 0; i < 4; ++i) {
                int e = i * 2048 + t * 8;
                int r = e >> 6, c = e & 63;
                const float* src = Af + (size_t)(m0 + r) * K + (k0 + c);
                float4 v0 = *(const float4*)src;
                float4 v1 = *(const float4*)(src + 4);
                bf16x8 pk;
                pk[0] = (short)f32_bf16_rne(v0.x); pk[1] = (short)f32_bf16_rne(v0.y);
                pk[2] = (short)f32_bf16_rne(v0.z); pk[3] = (short)f32_bf16_rne(v0.w);
                pk[4] = (short)f32_bf16_rne(v1.x); pk[5] = (short)f32_bf16_rne(v1.y);
                pk[6] = (short)f32_bf16_rne(v1.z); pk[7] = (short)f32_bf16_rne(v1.w);
                int byte = (r * 128 + c * 2) ^ ((r & 7) << 4);
                *(bf16x8*)((char*)sA + byte) = pk;
            }
        }
        __syncthreads();

#pragma unroll
        for (int ks = 0; ks < 2; ++ks) {
            const int kk = ks * 32 + ((lane >> 4) << 3);
            bf16x8 afr[4], bfr[4];
#pragma unroll
            for (int m = 0; m < 4; ++m) {
                int r = wr * 64 + m * 16 + (lane & 15);
                int byte = (r * 128 + kk * 2) ^ ((r & 7) << 4);
                afr[m] = *(const bf16x8*)((const char*)sA + byte);
            }
#pragma unroll
            for (int n = 0; n < 4; ++n) {
                int r = wc * 64 + n * 16 + (lane & 15);
                int byte = (r * 128 + kk * 2) ^ ((r & 7) << 4);
                bfr[n] = *(const bf16x8*)((const char*)sB + byte);
            }
#pragma unroll
            for (int m = 0; m < 4; ++m)
#pragma unroll
                for (int n = 0; n < 4; ++n)
                    acc[m][n] = __builtin_amdgcn_mfma_f32_16x16x32_bf16(
                        afr[m], bfr[n], acc[m][n], 0, 0, 0);
        }
        __syncthreads();
    }

    const float s = *scale_p;
#pragma unroll
    for (int m = 0; m < 4; ++m)
#pragma unroll
        for (int n = 0; n < 4; ++n) {
            const int col = n0 + wc * 64 + n * 16 + (lane & 15);
            const int rbase = m0 + wr * 64 + m * 16 + ((lane >> 4) << 2);
#pragma unroll
            for (int j = 0; j < 4; ++j)
                C[(size_t)(rbase + j) * N + col] = s * acc[m][n][j];
        }
}

// ---------- last-resort naive path ----------
__global__ void naive_qgemm(const float* __restrict__ X, const float* __restrict__ W,
                            float* __restrict__ out, const float* __restrict__ scale_p,
                            int M) {
    const int col = blockIdx.x * 256 + threadIdx.x;
    const int row = blockIdx.y;
    const float s = *scale_p;
    const float inv = 1.0f / s;
    const float* xr = X + (size_t)row * IN_F;
    const float* wrow = W + (size_t)col * IN_F;
    float acc = 0.f;
    for (int k = 0; k < IN_F; ++k) {
        float q = fminf(fmaxf(rintf(wrow[k] * inv), -2.f), 2.f);
        acc += xr[k] * q;
    }
    out[(size_t)row * OUT_F + col] = acc * s;
}

extern "C" void kernel_launch(void* const* d_in, const int* in_sizes, int n_in,
                              void* d_out, int out_size, void* d_ws, size_t ws_size,
                              hipStream_t stream) {
    const float* x = (const float*)d_in[0];
    const float* W = (const float*)d_in[1];
    float* out = (float*)d_out;
    const int M = in_sizes[0] / IN_F;  // 8192
    const int K = IN_F, N = OUT_F;

    char* ws = (char*)d_ws;
    const size_t OFF_PART = 512;
    const size_t OFF_WQ = OFF_PART + 4096 * sizeof(float);
    const size_t WQ_BYTES = (size_t)N * K * sizeof(ushort);
    const size_t OFF_XH = OFF_WQ + WQ_BYTES;
    const size_t XH_BYTES = (size_t)M * K * sizeof(ushort);
    float* scale = (float*)(ws + 0);
    float* part = (float*)(ws + OFF_PART);
    ushort* wq = (ushort*)(ws + OFF_WQ);
    ushort* xh = (ushort*)(ws + OFF_XH);

    if (ws_size < OFF_WQ) return;

    reduce_abs1<<<4096, 256, 0, stream>>>(W, part);
    reduce_abs2<<<1, 256, 0, stream>>>(part, scale);

    if (ws_size >= OFF_XH + XH_BYTES && (M % 256) == 0 && (N % 256) == 0) {
        quantize_w<<<(N * K / 4) / 256, 256, 0, stream>>>(W, wq, scale);
        cast_x<<<(M * K / 4) / 256, 256, 0, stream>>>(x, xh);
        (void)hipFuncSetAttribute((const void*)qgemm256,
                                  hipFuncAttributeMaxDynamicSharedMemorySize,
                                  131072);
        qgemm256<<<(M / 256) * (N / 256), 512, 131072, stream>>>(
            xh, wq, out, scale, M, N, K);
    } else if (ws_size >= OFF_XH + XH_BYTES) {
        quantize_w<<<(N * K / 4) / 256, 256, 0, stream>>>(W, wq, scale);
        cast_x<<<(M * K / 4) / 256, 256, 0, stream>>>(x, xh);
        qgemm<true><<<(M / 128) * (N / 128), 256, 0, stream>>>(xh, wq, out, scale, M, N, K);
    } else if (ws_size >= OFF_WQ + WQ_BYTES) {
        quantize_w<<<(N * K / 4) / 256, 256, 0, stream>>>(W, wq, scale);
        qgemm<false><<<(M / 128) * (N / 128), 256, 0, stream>>>(x, wq, out, scale, M, N, K);
    } else {
        naive_qgemm<<<dim3(N / 256, M), 256, 0, stream>>>(x, W, out, scale, M);
    }
}